// Round 1
// baseline (52.834 us; speedup 1.0000x reference)
//
#include <hip/hip_runtime.h>
#include <hip/hip_bf16.h>
#include <float.h>

#define VOCAB 128256
#define HID 256
#define NLANG 100
#define BATCH 64
#define SEQ 2048

#define LTILES 7                       // 7*16 = 112 >= 100 langs
#define KK 8                           // 256 / 32
#define TOK_PER_BLOCK 256
#define CHUNKS (SEQ / TOK_PER_BLOCK)   // 8
#define PAD_L (LTILES * 16)            // 112

typedef __attribute__((ext_vector_type(8))) short bf16x8;  // 8 bf16 in 4 VGPRs
typedef __attribute__((ext_vector_type(4))) float f32x4;

// fp32 -> bf16 bits, round-to-nearest-even
__device__ inline short f2bf(float f) {
    unsigned u = __builtin_bit_cast(unsigned, f);
    u = (u + 0x7fffu + ((u >> 16) & 1u)) >> 16;
    return (short)u;
}

// Kernel 1: per (batch, seq-chunk) block: gather+weight -> bf16 MFMA vs proj_w
// -> max over the chunk's 256 tokens. Writes partial[b][chunk][PAD_L].
__global__ __launch_bounds__(256, 2) void ld_score_kernel(
    const int* __restrict__ token_ids,
    const float* __restrict__ embeddings,
    const float* __restrict__ token_weights,
    const float* __restrict__ proj_w,
    float* __restrict__ partial)
{
    // proj_w staged in LDS already in B-fragment layout:
    // bs[lt][kk][lane] holds the 8 bf16 that lane needs for (lt,kk):
    //   B[k = kk*32 + (lane>>4)*8 + j][col = lt*16 + (lane&15)]
    // proj_w is (NLANG, HID) = B^T, so the 8 k's are contiguous in memory.
    __shared__ short bs[LTILES][KK][64][8];     // 57344 B
    __shared__ float wmax[4][LTILES][16];       // 1792 B

    const int t = threadIdx.x;
    const int lane = t & 63;
    const int w = t >> 6;

    // ---- stage proj_w -> LDS (bf16 fragments); 7*8*64 = 3584 frags / 256 thr = 14 each
    for (int i = 0; i < 14; ++i) {
        int f   = i * 256 + t;
        int fl  = f & 63;
        int fkk = (f >> 6) & 7;
        int flt = f >> 9;
        int row  = flt * 16 + (fl & 15);
        int colb = fkk * 32 + (fl >> 4) * 8;
        short v[8];
        if (row < NLANG) {
            const float* p = proj_w + row * HID + colb;
            float4 p0 = *reinterpret_cast<const float4*>(p);
            float4 p1 = *reinterpret_cast<const float4*>(p + 4);
            v[0] = f2bf(p0.x); v[1] = f2bf(p0.y); v[2] = f2bf(p0.z); v[3] = f2bf(p0.w);
            v[4] = f2bf(p1.x); v[5] = f2bf(p1.y); v[6] = f2bf(p1.z); v[7] = f2bf(p1.w);
        } else {
            #pragma unroll
            for (int j = 0; j < 8; ++j) v[j] = 0;
        }
        #pragma unroll
        for (int j = 0; j < 8; ++j) bs[flt][fkk][fl][j] = v[j];
    }
    __syncthreads();

    const int b     = blockIdx.x / CHUNKS;
    const int chunk = blockIdx.x % CHUNKS;
    const int s0    = chunk * TOK_PER_BLOCK;

    const int tt = lane & 15;   // A-fragment row (token within 16-tile)
    const int kg = lane >> 4;   // k-group

    float rmax[LTILES];
    #pragma unroll
    for (int lt = 0; lt < LTILES; ++lt) rmax[lt] = -FLT_MAX;

    for (int it = 0; it < TOK_PER_BLOCK / 64; ++it) {   // 4 tiles per wave
        const int s   = s0 + (it * 4 + w) * 16;
        const int tid = token_ids[b * SEQ + s + tt];
        const float wt = token_weights[tid];
        const float* erow = embeddings + (size_t)tid * HID + kg * 8;

        // A fragments: lane holds emb[token tt][kk*32 + kg*8 .. +8] * wt, bf16
        bf16x8 a[KK];
        #pragma unroll
        for (int kk = 0; kk < KK; ++kk) {
            float4 p0 = *reinterpret_cast<const float4*>(erow + kk * 32);
            float4 p1 = *reinterpret_cast<const float4*>(erow + kk * 32 + 4);
            bf16x8 av;
            av[0] = f2bf(p0.x * wt); av[1] = f2bf(p0.y * wt);
            av[2] = f2bf(p0.z * wt); av[3] = f2bf(p0.w * wt);
            av[4] = f2bf(p1.x * wt); av[5] = f2bf(p1.y * wt);
            av[6] = f2bf(p1.z * wt); av[7] = f2bf(p1.w * wt);
            a[kk] = av;
        }

        #pragma unroll
        for (int lt = 0; lt < LTILES; ++lt) {
            f32x4 acc = {0.f, 0.f, 0.f, 0.f};
            #pragma unroll
            for (int kk = 0; kk < KK; ++kk) {
                bf16x8 bv = *reinterpret_cast<const bf16x8*>(&bs[lt][kk][lane][0]);
                acc = __builtin_amdgcn_mfma_f32_16x16x32_bf16(a[kk], bv, acc, 0, 0, 0);
            }
            // D layout: col(lang) = lane&15, row(token) = (lane>>4)*4 + reg.
            // Max over this lane's 4 tokens; cross-lane token reduce comes later.
            float m = fmaxf(fmaxf(acc[0], acc[1]), fmaxf(acc[2], acc[3]));
            rmax[lt] = fmaxf(rmax[lt], m);
        }
    }

    // max across the 4 k-groups (lanes sharing lane&15) -> max over all 16 rows
    #pragma unroll
    for (int lt = 0; lt < LTILES; ++lt) {
        float m = rmax[lt];
        m = fmaxf(m, __shfl_xor(m, 16, 64));
        m = fmaxf(m, __shfl_xor(m, 32, 64));
        rmax[lt] = m;
    }

    if (kg == 0) {
        #pragma unroll
        for (int lt = 0; lt < LTILES; ++lt) wmax[w][lt][tt] = rmax[lt];
    }
    __syncthreads();

    if (t < PAD_L) {
        int lt = t >> 4, li = t & 15;
        float m = fmaxf(fmaxf(wmax[0][lt][li], wmax[1][lt][li]),
                        fmaxf(wmax[2][lt][li], wmax[3][lt][li]));
        partial[(b * CHUNKS + chunk) * PAD_L + t] = m;
    }
}

// Kernel 2: reduce chunks, add bias (max(x)+b == max(x+b), b is per-lang).
__global__ void ld_reduce_kernel(const float* __restrict__ partial,
                                 const float* __restrict__ proj_b,
                                 float* __restrict__ out)
{
    const int b = blockIdx.x;
    const int l = threadIdx.x;
    if (l >= NLANG) return;
    float m = -FLT_MAX;
    #pragma unroll
    for (int c = 0; c < CHUNKS; ++c)
        m = fmaxf(m, partial[(b * CHUNKS + c) * PAD_L + l]);
    out[b * NLANG + l] = m + proj_b[l];
}

extern "C" void kernel_launch(void* const* d_in, const int* in_sizes, int n_in,
                              void* d_out, int out_size, void* d_ws, size_t ws_size,
                              hipStream_t stream) {
    const int*   token_ids     = (const int*)d_in[0];
    const float* embeddings    = (const float*)d_in[1];
    const float* token_weights = (const float*)d_in[2];
    const float* proj_w        = (const float*)d_in[3];
    const float* proj_b        = (const float*)d_in[4];
    float* out = (float*)d_out;
    float* partial = (float*)d_ws;   // BATCH*CHUNKS*PAD_L*4 = 229376 B

    ld_score_kernel<<<BATCH * CHUNKS, 256, 0, stream>>>(
        token_ids, embeddings, token_weights, proj_w, partial);
    ld_reduce_kernel<<<BATCH, 128, 0, stream>>>(partial, proj_b, out);
}